// Round 3
// baseline (710.139 us; speedup 1.0000x reference)
//
#include <hip/hip_runtime.h>
#include <hip/hip_bf16.h>
#include <stdint.h>

typedef unsigned short u16;
typedef __attribute__((ext_vector_type(8))) short bf16x8;
typedef __attribute__((ext_vector_type(4))) float f32x4;

#define LDS_AS __attribute__((address_space(3)))
#define GLB_AS __attribute__((address_space(1)))

// T=1024, B=8, E=1024, H=16, hd=64, N=B*H=128, M=T*B=8192

__device__ __forceinline__ u16 f2bf(float f) {
  union { float f; uint32_t u; } v; v.f = f;
  uint32_t u = v.u;
  u += 0x7FFFu + ((u >> 16) & 1u);   // RNE
  return (u16)(u >> 16);
}

__device__ __forceinline__ f32x4 mfma16(bf16x8 a, bf16x8 b, f32x4 c) {
  return __builtin_amdgcn_mfma_f32_16x16x32_bf16(a, b, c, 0, 0, 0);
}

__device__ __forceinline__ void gll16(const void* g, void* l) {
  __builtin_amdgcn_global_load_lds((const GLB_AS void*)(uintptr_t)g,
                                   (LDS_AS void*)(uintptr_t)l, 16, 0, 0);
}

// ---------------- fp32 -> bf16 converts, batched ----------------
__global__ __launch_bounds__(256) void k_cvt3(
    const float* __restrict__ s0, const float* __restrict__ s1, const float* __restrict__ s2,
    u16* __restrict__ d0, u16* __restrict__ d1, u16* __restrict__ d2) {
  const float* s = blockIdx.y == 0 ? s0 : (blockIdx.y == 1 ? s1 : s2);
  u16* d = blockIdx.y == 0 ? d0 : (blockIdx.y == 1 ? d1 : d2);
  int i = (blockIdx.x * 256 + threadIdx.x) * 4;
  float4 v = *reinterpret_cast<const float4*>(s + i);
  ushort4 o;
  o.x = f2bf(v.x); o.y = f2bf(v.y); o.z = f2bf(v.z); o.w = f2bf(v.w);
  *reinterpret_cast<ushort4*>(d + i) = o;
}

__global__ __launch_bounds__(256) void k_cvt4(
    const float* __restrict__ s0, const float* __restrict__ s1,
    const float* __restrict__ s2, const float* __restrict__ s3,
    u16* __restrict__ d0, u16* __restrict__ d1, u16* __restrict__ d2, u16* __restrict__ d3) {
  const float* s = blockIdx.y == 0 ? s0 : (blockIdx.y == 1 ? s1 : (blockIdx.y == 2 ? s2 : s3));
  u16* d = blockIdx.y == 0 ? d0 : (blockIdx.y == 1 ? d1 : (blockIdx.y == 2 ? d2 : d3));
  int i = (blockIdx.x * 256 + threadIdx.x) * 4;
  float4 v = *reinterpret_cast<const float4*>(s + i);
  ushort4 o;
  o.x = f2bf(v.x); o.y = f2bf(v.y); o.z = f2bf(v.z); o.w = f2bf(v.w);
  *reinterpret_cast<ushort4*>(d + i) = o;
}

// ---------------- GEMM core: C[i,j] = dot(A[i,:], Bw[j,:]) + bias[j] ----------------
// 128x128 tile, 4 waves (2x2), BK=64. fp32out: fp32 at [i*1024+j] (nt);
// else bf16*scale at [(b*16+h)*1024+t][d]
__device__ __forceinline__ void gemm_core(
    const u16* __restrict__ A, const u16* __restrict__ Bw,
    const float* __restrict__ bias, void* __restrict__ outp,
    float scale, bool fp32out)
{
  __shared__ u16 aLds[128 * 64];
  __shared__ u16 bLds[128 * 64];
  const int tid = threadIdx.x;
  const int w = tid >> 6, lane = tid & 63;
  const int fr = lane & 15, fh = lane >> 4;
  const int m0 = blockIdx.x * 128, n0 = blockIdx.y * 128;
  const int wr = w >> 1, wc = w & 1;
  const int srow = tid >> 3, scol = (tid & 7) * 8;

  f32x4 zero4 = {0.f, 0.f, 0.f, 0.f};
  f32x4 acc[4][4];
#pragma unroll
  for (int i = 0; i < 4; i++)
#pragma unroll
    for (int j = 0; j < 4; j++) acc[i][j] = zero4;

  const u16* ag = A + (size_t)(m0 + srow) * 1024 + scol;
  const u16* bg = Bw + (size_t)(n0 + srow) * 1024 + scol;

  for (int k0 = 0; k0 < 1024; k0 += 64) {
#pragma unroll
    for (int it = 0; it < 4; ++it) {
      gll16(ag + (size_t)it * 32 * 1024 + k0, aLds + it * 2048 + w * 512);
      gll16(bg + (size_t)it * 32 * 1024 + k0, bLds + it * 2048 + w * 512);
    }
    __syncthreads();
#pragma unroll
    for (int ks = 0; ks < 2; ++ks) {
      bf16x8 af[4], bfr[4];
#pragma unroll
      for (int mi = 0; mi < 4; mi++)
        af[mi] = *reinterpret_cast<const bf16x8*>(&aLds[(wr * 64 + mi * 16 + fr) * 64 + ks * 32 + fh * 8]);
#pragma unroll
      for (int nj = 0; nj < 4; nj++)
        bfr[nj] = *reinterpret_cast<const bf16x8*>(&bLds[(wc * 64 + nj * 16 + fr) * 64 + ks * 32 + fh * 8]);
#pragma unroll
      for (int mi = 0; mi < 4; mi++)
#pragma unroll
        for (int nj = 0; nj < 4; nj++)
          acc[mi][nj] = mfma16(af[mi], bfr[nj], acc[mi][nj]);
    }
    __syncthreads();
  }

#pragma unroll
  for (int nj = 0; nj < 4; nj++) {
    int j = n0 + wc * 64 + nj * 16 + fr;
    float bj = bias[j];
#pragma unroll
    for (int mi = 0; mi < 4; mi++) {
#pragma unroll
      for (int r = 0; r < 4; r++) {
        int i = m0 + wr * 64 + mi * 16 + fh * 4 + r;
        float v = acc[mi][nj][r] + bj;
        if (fp32out) {
          __builtin_nontemporal_store(v, &((float*)outp)[(size_t)i * 1024 + j]);
        } else {
          v *= scale;
          int t = i >> 3, b = i & 7;
          int h = j >> 6, d = j & 63;
          ((u16*)outp)[((size_t)((b * 16 + h) * 1024 + t)) * 64 + d] = f2bf(v);
        }
      }
    }
  }
}

__global__ __launch_bounds__(256) void k_gemm_qkv(
    const u16* __restrict__ xq, const u16* __restrict__ xk, const u16* __restrict__ xv,
    const u16* __restrict__ wq, const u16* __restrict__ wk, const u16* __restrict__ wv,
    const float* __restrict__ bq, const float* __restrict__ bk, const float* __restrict__ bv,
    u16* __restrict__ qo, u16* __restrict__ ko, u16* __restrict__ vo)
{
  int z = blockIdx.z;
  const u16* A = z == 0 ? xq : (z == 1 ? xk : xv);
  const u16* Bw = z == 0 ? wq : (z == 1 ? wk : wv);
  const float* bias = z == 0 ? bq : (z == 1 ? bk : bv);
  u16* o = z == 0 ? qo : (z == 1 ? ko : vo);
  float scale = z == 0 ? 0.125f : 1.0f;
  gemm_core(A, Bw, bias, o, scale, false);
}

__global__ __launch_bounds__(256) void k_gemm_o(
    const u16* __restrict__ A, const u16* __restrict__ Bw,
    const float* __restrict__ bias, float* __restrict__ outp)
{
  gemm_core(A, Bw, bias, outp, 1.0f, true);
}

// ---------------- V transpose: vb [n][t][64] -> vt [n][64][1024] ----------------
__global__ __launch_bounds__(256) void k_transpose(const u16* __restrict__ vb, u16* __restrict__ vt) {
  __shared__ u16 tile[64][72];
  int n = blockIdx.y, t0 = blockIdx.x * 64;
  int tid = threadIdx.x;
  int r = tid >> 2, c0 = (tid & 3) * 16;
  const u16* src = vb + ((size_t)n * 1024 + t0 + r) * 64 + c0;
#pragma unroll
  for (int ii = 0; ii < 16; ++ii) tile[c0 + ii][r] = src[ii];
  __syncthreads();
  int d = tid >> 2;
  u16* dst = vt + ((size_t)(n * 64) + d) * 1024 + t0 + c0;
  *reinterpret_cast<uint4*>(dst)     = *reinterpret_cast<const uint4*>(&tile[d][c0]);
  *reinterpret_cast<uint4*>(dst + 8) = *reinterpret_cast<const uint4*>(&tile[d][c0 + 8]);
}

// ---------------- flash attention step: one 64-s block for one t-block ----------------
// lds_k: 64x64 bf16 K tile, XOR-swizzled (byte col ^= (row&7)<<4)
// lds_p: per-wave 16x64 bf16 P tile, same swizzle; vf: V tile frags in regs
__device__ __forceinline__ void attn_step(
    const u16* lds_k, u16* lds_p, const bf16x8 (&vf)[2][4],
    int sb, int tb_, int w, int fr, int fh,
    bf16x8 qf0, bf16x8 qf1,
    f32x4 (&oacc)[4], float (&m4)[4], float (&l4)[4])
{
  int t0 = tb_ * 64 + w * 16;
  f32x4 dd[4];
#pragma unroll
  for (int ss = 0; ss < 4; ++ss) {
    int row = ss * 16 + fr;
    const u16* kr = lds_k + row * 64;
    int c0 = (fh * 16) ^ ((row & 7) << 4);
    int c1 = (64 + fh * 16) ^ ((row & 7) << 4);
    bf16x8 kf0 = *reinterpret_cast<const bf16x8*>(kr + (c0 >> 1));
    bf16x8 kf1 = *reinterpret_cast<const bf16x8*>(kr + (c1 >> 1));
    f32x4 z = {0.f, 0.f, 0.f, 0.f};
    z = mfma16(qf0, kf0, z);
    dd[ss] = mfma16(qf1, kf1, z);
  }
  if (sb == tb_) {   // diagonal block: causal mask
#pragma unroll
    for (int ss = 0; ss < 4; ++ss) {
      int s_c = sb * 64 + ss * 16 + fr;
#pragma unroll
      for (int r = 0; r < 4; ++r)
        if (s_c > t0 + fh * 4 + r) dd[ss][r] = -3.0e38f;
    }
  }
  float mn[4], scale[4];
#pragma unroll
  for (int r = 0; r < 4; ++r) {
    float bm = fmaxf(fmaxf(dd[0][r], dd[1][r]), fmaxf(dd[2][r], dd[3][r]));
#pragma unroll
    for (int bmk = 1; bmk < 16; bmk <<= 1)
      bm = fmaxf(bm, __shfl_xor(bm, bmk, 64));
    mn[r] = fmaxf(m4[r], bm);
    scale[r] = __expf(m4[r] - mn[r]);
    m4[r] = mn[r];
  }
#pragma unroll
  for (int ss = 0; ss < 4; ++ss) {
#pragma unroll
    for (int r = 0; r < 4; ++r) {
      float p = __expf(dd[ss][r] - mn[r]);
      dd[ss][r] = p;
      int row = fh * 4 + r;
      int cb = ((ss * 16 + fr) * 2) ^ ((row & 7) << 4);
      lds_p[row * 64 + (cb >> 1)] = f2bf(p);
    }
  }
#pragma unroll
  for (int r = 0; r < 4; ++r) {
    float s = (dd[0][r] + dd[1][r]) + (dd[2][r] + dd[3][r]);
#pragma unroll
    for (int bmk = 1; bmk < 16; bmk <<= 1)
      s += __shfl_xor(s, bmk, 64);
    l4[r] = l4[r] * scale[r] + s;
#pragma unroll
    for (int db = 0; db < 4; ++db) oacc[db][r] *= scale[r];
  }
  asm volatile("s_waitcnt lgkmcnt(0)" ::: "memory");
  __builtin_amdgcn_sched_barrier(0);
#pragma unroll
  for (int ks = 0; ks < 2; ++ks) {
    int pc = (ks * 64 + fh * 16) ^ ((fr & 7) << 4);
    bf16x8 pa = *reinterpret_cast<const bf16x8*>(lds_p + fr * 64 + (pc >> 1));
#pragma unroll
    for (int db = 0; db < 4; ++db)
      oacc[db] = mfma16(pa, vf[ks][db], oacc[db]);
  }
}

// ---------------- attention: grid (n=128, j=8); block does t-blocks {15-j, j} ----------------
__global__ __launch_bounds__(256) void k_attn(
    const u16* __restrict__ qb, const u16* __restrict__ kb, const u16* __restrict__ vt,
    float* __restrict__ m_ws, float* __restrict__ l_ws, u16* __restrict__ attn_pre)
{
  __shared__ u16 kT[2][64 * 64];
  __shared__ u16 pT[4][16 * 64];
  int tid = threadIdx.x, w = tid >> 6, lane = tid & 63;
  int fr = lane & 15, fh = lane >> 4;
  int n = blockIdx.x, j = blockIdx.y;
  int tbH = 15 - j, tbL = j;
  const u16* kb_n = kb + (size_t)n * 1024 * 64;
  const u16* vt_n = vt + (size_t)n * 64 * 1024;

  bf16x8 qfH0, qfH1, qfL0, qfL1;
  {
    const u16* q = qb + ((size_t)n * 1024 + tbH * 64 + w * 16 + fr) * 64;
    qfH0 = *reinterpret_cast<const bf16x8*>(q + fh * 8);
    qfH1 = *reinterpret_cast<const bf16x8*>(q + 32 + fh * 8);
    q = qb + ((size_t)n * 1024 + tbL * 64 + w * 16 + fr) * 64;
    qfL0 = *reinterpret_cast<const bf16x8*>(q + fh * 8);
    qfL1 = *reinterpret_cast<const bf16x8*>(q + 32 + fh * 8);
  }
  f32x4 oaccH[4], oaccL[4];
  float mH[4], lH[4], mL[4], lL[4];
#pragma unroll
  for (int i = 0; i < 4; ++i) {
    oaccH[i] = (f32x4){0.f, 0.f, 0.f, 0.f};
    oaccL[i] = (f32x4){0.f, 0.f, 0.f, 0.f};
    mH[i] = -3.0e38f; lH[i] = 0.f; mL[i] = -3.0e38f; lL[i] = 0.f;
  }

  auto stage = [&](int buf, int sb) {
#pragma unroll
    for (int it = 0; it < 2; ++it) {
      int rbase = w * 16 + it * 8;
      int row = rbase + (lane >> 3);
      int colb = ((lane & 7) * 16) ^ ((lane >> 3) << 4);
      const u16* src = kb_n + ((size_t)(sb * 64 + row)) * 64 + (colb >> 1);
      gll16(src, &kT[buf][rbase * 64]);
    }
  };

  stage(0, 0);
  asm volatile("s_waitcnt vmcnt(0)" ::: "memory");
  __syncthreads();
  int cur = 0;
  for (int sb = 0; sb <= tbH; ++sb) {
    if (sb < tbH) stage(cur ^ 1, sb + 1);
    // V tile for this sb (shared by H and L steps) — issue early, hides L2 latency
    bf16x8 vf[2][4];
#pragma unroll
    for (int ks = 0; ks < 2; ++ks)
#pragma unroll
      for (int db = 0; db < 4; ++db)
        vf[ks][db] = *reinterpret_cast<const bf16x8*>(
            vt_n + ((size_t)(db * 16 + fr)) * 1024 + sb * 64 + ks * 32 + fh * 8);
    attn_step(kT[cur], pT[w], vf, sb, tbH, w, fr, fh, qfH0, qfH1, oaccH, mH, lH);
    if (sb <= tbL)
      attn_step(kT[cur], pT[w], vf, sb, tbL, w, fr, fh, qfL0, qfL1, oaccL, mL, lL);
    asm volatile("s_waitcnt vmcnt(0)" ::: "memory");
    __syncthreads();
    cur ^= 1;
  }

  int b_ = n >> 4, h_ = n & 15;
  {
    int t0 = tbH * 64 + w * 16;
    if (fr == 0) {
#pragma unroll
      for (int r = 0; r < 4; ++r) {
        m_ws[n * 1024 + t0 + fh * 4 + r] = mH[r];
        l_ws[n * 1024 + t0 + fh * 4 + r] = lH[r];
      }
    }
#pragma unroll
    for (int db = 0; db < 4; ++db)
#pragma unroll
      for (int r = 0; r < 4; ++r)
        attn_pre[((size_t)((t0 + fh * 4 + r) * 8 + b_)) * 1024 + h_ * 64 + db * 16 + fr] =
            f2bf(oaccH[db][r] / lH[r]);
  }
  {
    int t0 = tbL * 64 + w * 16;
    if (fr == 0) {
#pragma unroll
      for (int r = 0; r < 4; ++r) {
        m_ws[n * 1024 + t0 + fh * 4 + r] = mL[r];
        l_ws[n * 1024 + t0 + fh * 4 + r] = lL[r];
      }
    }
#pragma unroll
    for (int db = 0; db < 4; ++db)
#pragma unroll
      for (int r = 0; r < 4; ++r)
        attn_pre[((size_t)((t0 + fh * 4 + r) * 8 + b_)) * 1024 + h_ * 64 + db * 16 + fr] =
            f2bf(oaccL[db][r] / lL[r]);
  }
}

// ---------------- weights + avg: grid (pid=128, b=8); cells {pid, 255-pid} ----------------
// Stores via per-wave LDS transpose -> 256B-contiguous nontemporal dwordx4.
__global__ __launch_bounds__(256) void k_weights(
    const u16* __restrict__ qb, const u16* __restrict__ kb,
    const float* __restrict__ m_ws, const float* __restrict__ l_ws,
    float* __restrict__ wout, float* __restrict__ avg)
{
  __shared__ float sw[4][16 * 64];
  int pid = blockIdx.x, b = blockIdx.y;
  int tid = threadIdx.x;
  int w = tid >> 6, lane = tid & 63, fr = lane & 15, fh = lane >> 4;
  float* swv = sw[w];

#pragma unroll
  for (int cell = 0; cell < 2; ++cell) {
    int cid = cell ? (255 - pid) : pid;
    int tb = cid >> 4, sb = cid & 15;
    int t0 = tb * 64, s0 = sb * 64;

    if (sb > tb) {  // fully masked: zero weights (all h) + zero avg
      int zr = tid >> 2, zc = (tid & 3) * 16;
      f32x4 z = {0.f, 0.f, 0.f, 0.f};
#pragma unroll
      for (int h = 0; h < 16; ++h) {
        float* dst = &wout[(((size_t)(b * 16 + h) * 1024) + t0 + zr) * 1024 + s0 + zc];
        __builtin_nontemporal_store(z, (f32x4*)dst);
        __builtin_nontemporal_store(z, (f32x4*)(dst + 4));
        __builtin_nontemporal_store(z, (f32x4*)(dst + 8));
        __builtin_nontemporal_store(z, (f32x4*)(dst + 12));
      }
      float* da = &avg[((size_t)(b * 1024) + t0 + zr) * 1024 + s0 + zc];
      __builtin_nontemporal_store(z, (f32x4*)da);
      __builtin_nontemporal_store(z, (f32x4*)(da + 4));
      __builtin_nontemporal_store(z, (f32x4*)(da + 8));
      __builtin_nontemporal_store(z, (f32x4*)(da + 12));
      continue;
    }

    int t_r = t0 + w * 16;
    int t_g[4];
#pragma unroll
    for (int r = 0; r < 4; r++) t_g[r] = t_r + fh * 4 + r;

    f32x4 avg_acc[4];
#pragma unroll
    for (int cb = 0; cb < 4; cb++) avg_acc[cb] = (f32x4){0.f, 0.f, 0.f, 0.f};

    for (int h = 0; h < 16; ++h) {
      int n = b * 16 + h;
      const u16* qrow = qb + ((size_t)n * 1024 + t_r + fr) * 64;
      bf16x8 qf0 = *reinterpret_cast<const bf16x8*>(&qrow[fh * 8]);
      bf16x8 qf1 = *reinterpret_cast<const bf16x8*>(&qrow[32 + fh * 8]);
      float mr[4], li[4];
#pragma unroll
      for (int r = 0; r < 4; r++) {
        mr[r] = m_ws[n * 1024 + t_g[r]];
        li[r] = 1.0f / l_ws[n * 1024 + t_g[r]];
      }
#pragma unroll
      for (int cb = 0; cb < 4; ++cb) {
        const u16* krow = kb + ((size_t)n * 1024 + s0 + cb * 16 + fr) * 64;
        bf16x8 kf0 = *reinterpret_cast<const bf16x8*>(&krow[fh * 8]);
        bf16x8 kf1 = *reinterpret_cast<const bf16x8*>(&krow[32 + fh * 8]);
        f32x4 dd = {0.f, 0.f, 0.f, 0.f};
        dd = mfma16(qf0, kf0, dd);
        dd = mfma16(qf1, kf1, dd);
        int s_c = s0 + cb * 16 + fr;
#pragma unroll
        for (int r = 0; r < 4; r++) {
          float wv = (s_c <= t_g[r]) ? __expf(dd[r] - mr[r]) * li[r] : 0.f;
          avg_acc[cb][r] += wv;
          // LDS transpose stage: row = fh*4+r (local), col = cb*16+fr, XOR-swizzled 16B units
          int row = fh * 4 + r;
          int colx = (cb * 16 + fr) ^ ((row & 3) << 2);
          swv[row * 64 + colx] = wv;
        }
      }
      asm volatile("s_waitcnt lgkmcnt(0)" ::: "memory");
      __builtin_amdgcn_sched_barrier(0);
      // coalesced store: 4 instrs, each 4 rows x 256B contiguous
      float* wbase = &wout[(((size_t)n * 1024) + t_r) * 1024 + s0];
#pragma unroll
      for (int q = 0; q < 4; ++q) {
        int row = q * 4 + (lane >> 4);
        int colf = ((lane & 15) * 4) ^ ((row & 3) << 2);
        f32x4 v = *reinterpret_cast<const f32x4*>(&swv[row * 64 + colf]);
        __builtin_nontemporal_store(v, (f32x4*)(wbase + (size_t)row * 1024 + (lane & 15) * 4));
      }
      asm volatile("" ::: "memory");  // keep LDS reuse ordered across h iterations
    }
#pragma unroll
    for (int cb = 0; cb < 4; ++cb)
#pragma unroll
      for (int r = 0; r < 4; r++)
        __builtin_nontemporal_store(avg_acc[cb][r] * 0.0625f,
            &avg[((size_t)b * 1024 + t_g[r]) * 1024 + s0 + cb * 16 + fr]);
  }
}

// ---------------- launcher ----------------
extern "C" void kernel_launch(void* const* d_in, const int* in_sizes, int n_in,
                              void* d_out, int out_size, void* d_ws, size_t ws_size,
                              hipStream_t stream)
{
  const float* query = (const float*)d_in[0];
  const float* key_  = (const float*)d_in[1];
  const float* value = (const float*)d_in[2];
  const float* Wq = (const float*)d_in[5];
  const float* bq = (const float*)d_in[6];
  const float* Wk = (const float*)d_in[7];
  const float* bk = (const float*)d_in[8];
  const float* Wv = (const float*)d_in[9];
  const float* bv = (const float*)d_in[10];
  const float* Wo = (const float*)d_in[11];
  const float* bo = (const float*)d_in[12];

  char* ws = (char*)d_ws;
  size_t off = 0;
  auto alloc = [&](size_t bytes) { char* p = ws + off; off += (bytes + 255) & ~255ull; return p; };

  u16* xq   = (u16*)alloc(8192ull * 1024 * 2);
  u16* xk   = (u16*)alloc(8192ull * 1024 * 2);
  u16* xv   = (u16*)alloc(8192ull * 1024 * 2);
  u16* wqb  = (u16*)alloc(1024ull * 1024 * 2);
  u16* wkb  = (u16*)alloc(1024ull * 1024 * 2);
  u16* wvb  = (u16*)alloc(1024ull * 1024 * 2);
  u16* wob  = (u16*)alloc(1024ull * 1024 * 2);
  u16* qbuf = (u16*)alloc(128ull * 1024 * 64 * 2);
  u16* kbuf = (u16*)alloc(128ull * 1024 * 64 * 2);
  u16* vbuf = (u16*)alloc(128ull * 1024 * 64 * 2);
  u16* vtb  = (u16*)alloc(128ull * 64 * 1024 * 2);
  u16* apre = (u16*)alloc(8192ull * 1024 * 2);
  float* mws = (float*)alloc(128ull * 1024 * 4);
  float* lws = (float*)alloc(128ull * 1024 * 4);

  float* out_attn = (float*)d_out;                  // [1024,8,1024]
  float* out_avg  = out_attn + 8388608;             // [8,1024,1024]
  float* out_w    = out_avg + 8388608;              // [8,16,1024,1024]

  k_cvt3<<<dim3(8192, 3), 256, 0, stream>>>(query, key_, value, xq, xk, xv);
  k_cvt4<<<dim3(1024, 4), 256, 0, stream>>>(Wq, Wk, Wv, Wo, wqb, wkb, wvb, wob);

  k_gemm_qkv<<<dim3(64, 8, 3), 256, 0, stream>>>(xq, xk, xv, wqb, wkb, wvb,
                                                 bq, bk, bv, qbuf, kbuf, vbuf);

  k_transpose<<<dim3(16, 128), 256, 0, stream>>>(vbuf, vtb);
  k_attn<<<dim3(128, 8), 256, 0, stream>>>(qbuf, kbuf, vtb, mws, lws, apre);
  k_weights<<<dim3(128, 8), 256, 0, stream>>>(qbuf, kbuf, mws, lws, out_w, out_avg);
  k_gemm_o<<<dim3(64, 8), 256, 0, stream>>>(apre, wob, bo, out_attn);
}

// Round 4
// 465.815 us; speedup vs baseline: 1.5245x; 1.5245x over previous
//
#include <hip/hip_runtime.h>
#include <hip/hip_bf16.h>
#include <stdint.h>

typedef unsigned short u16;
typedef __attribute__((ext_vector_type(8))) short bf16x8;
typedef __attribute__((ext_vector_type(4))) float f32x4;

#define LDS_AS __attribute__((address_space(3)))
#define GLB_AS __attribute__((address_space(1)))

// T=1024, B=8, E=1024, H=16, hd=64, N=B*H=128, M=T*B=8192

__device__ __forceinline__ u16 f2bf(float f) {
  union { float f; uint32_t u; } v; v.f = f;
  uint32_t u = v.u;
  u += 0x7FFFu + ((u >> 16) & 1u);   // RNE
  return (u16)(u >> 16);
}

__device__ __forceinline__ f32x4 mfma16(bf16x8 a, bf16x8 b, f32x4 c) {
  return __builtin_amdgcn_mfma_f32_16x16x32_bf16(a, b, c, 0, 0, 0);
}

__device__ __forceinline__ void gll16(const void* g, void* l) {
  __builtin_amdgcn_global_load_lds((const GLB_AS void*)(uintptr_t)g,
                                   (LDS_AS void*)(uintptr_t)l, 16, 0, 0);
}

// ---------------- fp32 -> bf16 converts, batched ----------------
__global__ __launch_bounds__(256) void k_cvt3(
    const float* __restrict__ s0, const float* __restrict__ s1, const float* __restrict__ s2,
    u16* __restrict__ d0, u16* __restrict__ d1, u16* __restrict__ d2) {
  const float* s = blockIdx.y == 0 ? s0 : (blockIdx.y == 1 ? s1 : s2);
  u16* d = blockIdx.y == 0 ? d0 : (blockIdx.y == 1 ? d1 : d2);
  int i = (blockIdx.x * 256 + threadIdx.x) * 4;
  float4 v = *reinterpret_cast<const float4*>(s + i);
  ushort4 o;
  o.x = f2bf(v.x); o.y = f2bf(v.y); o.z = f2bf(v.z); o.w = f2bf(v.w);
  *reinterpret_cast<ushort4*>(d + i) = o;
}

__global__ __launch_bounds__(256) void k_cvt4(
    const float* __restrict__ s0, const float* __restrict__ s1,
    const float* __restrict__ s2, const float* __restrict__ s3,
    u16* __restrict__ d0, u16* __restrict__ d1, u16* __restrict__ d2, u16* __restrict__ d3) {
  const float* s = blockIdx.y == 0 ? s0 : (blockIdx.y == 1 ? s1 : (blockIdx.y == 2 ? s2 : s3));
  u16* d = blockIdx.y == 0 ? d0 : (blockIdx.y == 1 ? d1 : (blockIdx.y == 2 ? d2 : d3));
  int i = (blockIdx.x * 256 + threadIdx.x) * 4;
  float4 v = *reinterpret_cast<const float4*>(s + i);
  ushort4 o;
  o.x = f2bf(v.x); o.y = f2bf(v.y); o.z = f2bf(v.z); o.w = f2bf(v.w);
  *reinterpret_cast<ushort4*>(d + i) = o;
}

// ---------------- GEMM core: C[i,j] = dot(A[i,:], Bw[j,:]) + bias[j] ----------------
__device__ __forceinline__ void gemm_core(
    const u16* __restrict__ A, const u16* __restrict__ Bw,
    const float* __restrict__ bias, void* __restrict__ outp,
    float scale, bool fp32out)
{
  __shared__ u16 aLds[128 * 64];
  __shared__ u16 bLds[128 * 64];
  const int tid = threadIdx.x;
  const int w = tid >> 6, lane = tid & 63;
  const int fr = lane & 15, fh = lane >> 4;
  const int m0 = blockIdx.x * 128, n0 = blockIdx.y * 128;
  const int wr = w >> 1, wc = w & 1;
  const int srow = tid >> 3, scol = (tid & 7) * 8;

  f32x4 zero4 = {0.f, 0.f, 0.f, 0.f};
  f32x4 acc[4][4];
#pragma unroll
  for (int i = 0; i < 4; i++)
#pragma unroll
    for (int j = 0; j < 4; j++) acc[i][j] = zero4;

  const u16* ag = A + (size_t)(m0 + srow) * 1024 + scol;
  const u16* bg = Bw + (size_t)(n0 + srow) * 1024 + scol;

  for (int k0 = 0; k0 < 1024; k0 += 64) {
#pragma unroll
    for (int it = 0; it < 4; ++it) {
      gll16(ag + (size_t)it * 32 * 1024 + k0, aLds + it * 2048 + w * 512);
      gll16(bg + (size_t)it * 32 * 1024 + k0, bLds + it * 2048 + w * 512);
    }
    __syncthreads();
#pragma unroll
    for (int ks = 0; ks < 2; ++ks) {
      bf16x8 af[4], bfr[4];
#pragma unroll
      for (int mi = 0; mi < 4; mi++)
        af[mi] = *reinterpret_cast<const bf16x8*>(&aLds[(wr * 64 + mi * 16 + fr) * 64 + ks * 32 + fh * 8]);
#pragma unroll
      for (int nj = 0; nj < 4; nj++)
        bfr[nj] = *reinterpret_cast<const bf16x8*>(&bLds[(wc * 64 + nj * 16 + fr) * 64 + ks * 32 + fh * 8]);
#pragma unroll
      for (int mi = 0; mi < 4; mi++)
#pragma unroll
        for (int nj = 0; nj < 4; nj++)
          acc[mi][nj] = mfma16(af[mi], bfr[nj], acc[mi][nj]);
    }
    __syncthreads();
  }

#pragma unroll
  for (int nj = 0; nj < 4; nj++) {
    int j = n0 + wc * 64 + nj * 16 + fr;
    float bj = bias[j];
#pragma unroll
    for (int mi = 0; mi < 4; mi++) {
#pragma unroll
      for (int r = 0; r < 4; r++) {
        int i = m0 + wr * 64 + mi * 16 + fh * 4 + r;
        float v = acc[mi][nj][r] + bj;
        if (fp32out) {
          ((float*)outp)[(size_t)i * 1024 + j] = v;
        } else {
          v *= scale;
          int t = i >> 3, b = i & 7;
          int h = j >> 6, d = j & 63;
          ((u16*)outp)[((size_t)((b * 16 + h) * 1024 + t)) * 64 + d] = f2bf(v);
        }
      }
    }
  }
}

__global__ __launch_bounds__(256) void k_gemm_qkv(
    const u16* __restrict__ xq, const u16* __restrict__ xk, const u16* __restrict__ xv,
    const u16* __restrict__ wq, const u16* __restrict__ wk, const u16* __restrict__ wv,
    const float* __restrict__ bq, const float* __restrict__ bk, const float* __restrict__ bv,
    u16* __restrict__ qo, u16* __restrict__ ko, u16* __restrict__ vo)
{
  int z = blockIdx.z;
  const u16* A = z == 0 ? xq : (z == 1 ? xk : xv);
  const u16* Bw = z == 0 ? wq : (z == 1 ? wk : wv);
  const float* bias = z == 0 ? bq : (z == 1 ? bk : bv);
  u16* o = z == 0 ? qo : (z == 1 ? ko : vo);
  float scale = z == 0 ? 0.125f : 1.0f;
  gemm_core(A, Bw, bias, o, scale, false);
}

__global__ __launch_bounds__(256) void k_gemm_o(
    const u16* __restrict__ A, const u16* __restrict__ Bw,
    const float* __restrict__ bias, float* __restrict__ outp)
{
  gemm_core(A, Bw, bias, outp, 1.0f, true);
}

// ---------------- V transpose: vb [n][t][64] -> vt [n][64][1024] ----------------
__global__ __launch_bounds__(256) void k_transpose(const u16* __restrict__ vb, u16* __restrict__ vt) {
  __shared__ u16 tile[64][72];
  int n = blockIdx.y, t0 = blockIdx.x * 64;
  int tid = threadIdx.x;
  int r = tid >> 2, c0 = (tid & 3) * 16;
  const u16* src = vb + ((size_t)n * 1024 + t0 + r) * 64 + c0;
#pragma unroll
  for (int ii = 0; ii < 16; ++ii) tile[c0 + ii][r] = src[ii];
  __syncthreads();
  int d = tid >> 2;
  u16* dst = vt + ((size_t)(n * 64) + d) * 1024 + t0 + c0;
  *reinterpret_cast<uint4*>(dst)     = *reinterpret_cast<const uint4*>(&tile[d][c0]);
  *reinterpret_cast<uint4*>(dst + 8) = *reinterpret_cast<const uint4*>(&tile[d][c0 + 8]);
}

// ---------------- flash attention step: one 64-s block for one t-block ----------------
__device__ __forceinline__ void attn_step(
    const u16* lds_k, u16* lds_p, const bf16x8 (&vf)[2][4],
    int sb, int tb_, int w, int fr, int fh,
    bf16x8 qf0, bf16x8 qf1,
    f32x4 (&oacc)[4], float (&m4)[4], float (&l4)[4])
{
  int t0 = tb_ * 64 + w * 16;
  f32x4 dd[4];
#pragma unroll
  for (int ss = 0; ss < 4; ++ss) {
    int row = ss * 16 + fr;
    const u16* kr = lds_k + row * 64;
    int c0 = (fh * 16) ^ ((row & 7) << 4);
    int c1 = (64 + fh * 16) ^ ((row & 7) << 4);
    bf16x8 kf0 = *reinterpret_cast<const bf16x8*>(kr + (c0 >> 1));
    bf16x8 kf1 = *reinterpret_cast<const bf16x8*>(kr + (c1 >> 1));
    f32x4 z = {0.f, 0.f, 0.f, 0.f};
    z = mfma16(qf0, kf0, z);
    dd[ss] = mfma16(qf1, kf1, z);
  }
  if (sb == tb_) {   // diagonal block: causal mask
#pragma unroll
    for (int ss = 0; ss < 4; ++ss) {
      int s_c = sb * 64 + ss * 16 + fr;
#pragma unroll
      for (int r = 0; r < 4; ++r)
        if (s_c > t0 + fh * 4 + r) dd[ss][r] = -3.0e38f;
    }
  }
  float mn[4], scale[4];
#pragma unroll
  for (int r = 0; r < 4; ++r) {
    float bm = fmaxf(fmaxf(dd[0][r], dd[1][r]), fmaxf(dd[2][r], dd[3][r]));
#pragma unroll
    for (int bmk = 1; bmk < 16; bmk <<= 1)
      bm = fmaxf(bm, __shfl_xor(bm, bmk, 64));
    mn[r] = fmaxf(m4[r], bm);
    scale[r] = __expf(m4[r] - mn[r]);
    m4[r] = mn[r];
  }
#pragma unroll
  for (int ss = 0; ss < 4; ++ss) {
#pragma unroll
    for (int r = 0; r < 4; ++r) {
      float p = __expf(dd[ss][r] - mn[r]);
      dd[ss][r] = p;
      int row = fh * 4 + r;
      int cb = ((ss * 16 + fr) * 2) ^ ((row & 7) << 4);
      lds_p[row * 64 + (cb >> 1)] = f2bf(p);
    }
  }
#pragma unroll
  for (int r = 0; r < 4; ++r) {
    float s = (dd[0][r] + dd[1][r]) + (dd[2][r] + dd[3][r]);
#pragma unroll
    for (int bmk = 1; bmk < 16; bmk <<= 1)
      s += __shfl_xor(s, bmk, 64);
    l4[r] = l4[r] * scale[r] + s;
#pragma unroll
    for (int db = 0; db < 4; ++db) oacc[db][r] *= scale[r];
  }
  asm volatile("s_waitcnt lgkmcnt(0)" ::: "memory");
  __builtin_amdgcn_sched_barrier(0);
#pragma unroll
  for (int ks = 0; ks < 2; ++ks) {
    int pc = (ks * 64 + fh * 16) ^ ((fr & 7) << 4);
    bf16x8 pa = *reinterpret_cast<const bf16x8*>(lds_p + fr * 64 + (pc >> 1));
#pragma unroll
    for (int db = 0; db < 4; ++db)
      oacc[db] = mfma16(pa, vf[ks][db], oacc[db]);
  }
}

// ---------------- attention: grid (n=128, j=8); block does t-blocks {15-j, j} ----------------
__global__ __launch_bounds__(256) void k_attn(
    const u16* __restrict__ qb, const u16* __restrict__ kb, const u16* __restrict__ vt,
    float* __restrict__ m_ws, float* __restrict__ l_ws, u16* __restrict__ attn_pre)
{
  __shared__ u16 kT[2][64 * 64];
  __shared__ u16 pT[4][16 * 64];
  int tid = threadIdx.x, w = tid >> 6, lane = tid & 63;
  int fr = lane & 15, fh = lane >> 4;
  int n = blockIdx.x, j = blockIdx.y;
  int tbH = 15 - j, tbL = j;
  const u16* kb_n = kb + (size_t)n * 1024 * 64;
  const u16* vt_n = vt + (size_t)n * 64 * 1024;

  bf16x8 qfH0, qfH1, qfL0, qfL1;
  {
    const u16* q = qb + ((size_t)n * 1024 + tbH * 64 + w * 16 + fr) * 64;
    qfH0 = *reinterpret_cast<const bf16x8*>(q + fh * 8);
    qfH1 = *reinterpret_cast<const bf16x8*>(q + 32 + fh * 8);
    q = qb + ((size_t)n * 1024 + tbL * 64 + w * 16 + fr) * 64;
    qfL0 = *reinterpret_cast<const bf16x8*>(q + fh * 8);
    qfL1 = *reinterpret_cast<const bf16x8*>(q + 32 + fh * 8);
  }
  f32x4 oaccH[4], oaccL[4];
  float mH[4], lH[4], mL[4], lL[4];
#pragma unroll
  for (int i = 0; i < 4; ++i) {
    oaccH[i] = (f32x4){0.f, 0.f, 0.f, 0.f};
    oaccL[i] = (f32x4){0.f, 0.f, 0.f, 0.f};
    mH[i] = -3.0e38f; lH[i] = 0.f; mL[i] = -3.0e38f; lL[i] = 0.f;
  }

  auto stage = [&](int buf, int sb) {
#pragma unroll
    for (int it = 0; it < 2; ++it) {
      int rbase = w * 16 + it * 8;
      int row = rbase + (lane >> 3);
      int colb = ((lane & 7) * 16) ^ ((lane >> 3) << 4);
      const u16* src = kb_n + ((size_t)(sb * 64 + row)) * 64 + (colb >> 1);
      gll16(src, &kT[buf][rbase * 64]);
    }
  };

  stage(0, 0);
  asm volatile("s_waitcnt vmcnt(0)" ::: "memory");
  __syncthreads();
  int cur = 0;
  for (int sb = 0; sb <= tbH; ++sb) {
    if (sb < tbH) stage(cur ^ 1, sb + 1);
    bf16x8 vf[2][4];
#pragma unroll
    for (int ks = 0; ks < 2; ++ks)
#pragma unroll
      for (int db = 0; db < 4; ++db)
        vf[ks][db] = *reinterpret_cast<const bf16x8*>(
            vt_n + ((size_t)(db * 16 + fr)) * 1024 + sb * 64 + ks * 32 + fh * 8);
    attn_step(kT[cur], pT[w], vf, sb, tbH, w, fr, fh, qfH0, qfH1, oaccH, mH, lH);
    if (sb <= tbL)
      attn_step(kT[cur], pT[w], vf, sb, tbL, w, fr, fh, qfL0, qfL1, oaccL, mL, lL);
    asm volatile("s_waitcnt vmcnt(0)" ::: "memory");
    __syncthreads();
    cur ^= 1;
  }

  int b_ = n >> 4, h_ = n & 15;
  {
    int t0 = tbH * 64 + w * 16;
    if (fr == 0) {
#pragma unroll
      for (int r = 0; r < 4; ++r) {
        m_ws[n * 1024 + t0 + fh * 4 + r] = mH[r];
        l_ws[n * 1024 + t0 + fh * 4 + r] = lH[r];
      }
    }
#pragma unroll
    for (int db = 0; db < 4; ++db)
#pragma unroll
      for (int r = 0; r < 4; ++r)
        attn_pre[((size_t)((t0 + fh * 4 + r) * 8 + b_)) * 1024 + h_ * 64 + db * 16 + fr] =
            f2bf(oaccH[db][r] / lH[r]);
  }
  {
    int t0 = tbL * 64 + w * 16;
    if (fr == 0) {
#pragma unroll
      for (int r = 0; r < 4; ++r) {
        m_ws[n * 1024 + t0 + fh * 4 + r] = mL[r];
        l_ws[n * 1024 + t0 + fh * 4 + r] = lL[r];
      }
    }
#pragma unroll
    for (int db = 0; db < 4; ++db)
#pragma unroll
      for (int r = 0; r < 4; ++r)
        attn_pre[((size_t)((t0 + fh * 4 + r) * 8 + b_)) * 1024 + h_ * 64 + db * 16 + fr] =
            f2bf(oaccL[db][r] / lL[r]);
  }
}

// ---------------- weights + avg: row-panel streaming version ----------------
// grid = 256 blocks x 512 threads. pid&7 = b (XCD-grouped so K[b] stays L2-resident),
// pid>>3 = pr; block handles t-panels {pr, 63-pr} (16 rows each, causally balanced).
// Loops h inside => avg accumulates in registers. Wave w owns s-blocks w, w+8, ...
// Writes are dense 64KB runs (16 rows x 4KB) per (h, panel) => HBM row-buffer friendly.
__global__ __launch_bounds__(512) void k_weights(
    const u16* __restrict__ qb, const u16* __restrict__ kb,
    const float* __restrict__ m_ws, const float* __restrict__ l_ws,
    float* __restrict__ wout, float* __restrict__ avg)
{
  int pid = blockIdx.x;
  int b = pid & 7, pr = pid >> 3;
  int tid = threadIdx.x;
  int w = tid >> 6, lane = tid & 63, fr = lane & 15, fh = lane >> 4;
  f32x4 zero4 = {0.f, 0.f, 0.f, 0.f};

#pragma unroll
  for (int half = 0; half < 2; ++half) {
    int p = half ? (63 - pr) : pr;
    int t0 = p * 16;

    float avg_acc[8][4];
#pragma unroll
    for (int i = 0; i < 8; ++i)
#pragma unroll
      for (int r = 0; r < 4; ++r) avg_acc[i][r] = 0.f;

    for (int h = 0; h < 16; ++h) {
      int n = b * 16 + h;
      const u16* qrow = qb + ((size_t)n * 1024 + t0 + fr) * 64;
      bf16x8 qf0 = *reinterpret_cast<const bf16x8*>(&qrow[fh * 8]);
      bf16x8 qf1 = *reinterpret_cast<const bf16x8*>(&qrow[32 + fh * 8]);
      float mr[4], li[4];
#pragma unroll
      for (int r = 0; r < 4; ++r) {
        mr[r] = m_ws[n * 1024 + t0 + fh * 4 + r];
        li[r] = 1.0f / l_ws[n * 1024 + t0 + fh * 4 + r];
      }
      float* wrow = wout + ((size_t)n << 20) + ((size_t)t0 << 10);

#pragma unroll
      for (int i = 0; i < 8; ++i) {
        int sblk = w + i * 8;          // wave-uniform
        if (sblk <= p) {               // computed block (diag partially masked)
          const u16* krow = kb + ((size_t)n * 1024 + sblk * 16 + fr) * 64;
          bf16x8 kf0 = *reinterpret_cast<const bf16x8*>(&krow[fh * 8]);
          bf16x8 kf1 = *reinterpret_cast<const bf16x8*>(&krow[32 + fh * 8]);
          f32x4 dd = zero4;
          dd = mfma16(qf0, kf0, dd);
          dd = mfma16(qf1, kf1, dd);
          int s_rel = sblk * 16 + fr;  // s relative to 0; t_rel = fh*4+r
#pragma unroll
          for (int r = 0; r < 4; ++r) {
            float wv = (sblk < p || s_rel <= fh * 4 + r + t0 - t0 + (fh * 4 + r) * 0) ? 0.f : 0.f;
            // causal test: global s = s_rel, global t = t0 + fh*4 + r; within
            // diagonal block (sblk==p) s_rel - p*16 vs fh*4+r decides.
            bool valid = (sblk < p) || ((s_rel - p * 16) <= (fh * 4 + r));
            wv = valid ? __expf(dd[r] - mr[r]) * li[r] : 0.f;
            avg_acc[i][r] += wv;
            wrow[(size_t)(fh * 4 + r) * 1024 + s_rel] = wv;
          }
        } else {                        // fully-masked: dense zero fill
          float* zp = wrow + (size_t)(lane & 15) * 1024 + sblk * 16 + (lane >> 4) * 4;
          *reinterpret_cast<f32x4*>(zp) = zero4;
        }
      }
    }
    // avg for this (b, panel): rows t0..t0+15, all s
    float* arow = avg + (((size_t)b << 10) + t0) * 1024;
#pragma unroll
    for (int i = 0; i < 8; ++i) {
      int s_rel = (w + i * 8) * 16 + fr;
#pragma unroll
      for (int r = 0; r < 4; ++r)
        arow[(size_t)(fh * 4 + r) * 1024 + s_rel] = avg_acc[i][r] * 0.0625f;
    }
  }
}

// ---------------- launcher ----------------
extern "C" void kernel_launch(void* const* d_in, const int* in_sizes, int n_in,
                              void* d_out, int out_size, void* d_ws, size_t ws_size,
                              hipStream_t stream)
{
  const float* query = (const float*)d_in[0];
  const float* key_  = (const float*)d_in[1];
  const float* value = (const float*)d_in[2];
  const float* Wq = (const float*)d_in[5];
  const float* bq = (const float*)d_in[6];
  const float* Wk = (const float*)d_in[7];
  const float* bk = (const float*)d_in[8];
  const float* Wv = (const float*)d_in[9];
  const float* bv = (const float*)d_in[10];
  const float* Wo = (const float*)d_in[11];
  const float* bo = (const float*)d_in[12];

  char* ws = (char*)d_ws;
  size_t off = 0;
  auto alloc = [&](size_t bytes) { char* p = ws + off; off += (bytes + 255) & ~255ull; return p; };

  u16* xq   = (u16*)alloc(8192ull * 1024 * 2);
  u16* xk   = (u16*)alloc(8192ull * 1024 * 2);
  u16* xv   = (u16*)alloc(8192ull * 1024 * 2);
  u16* wqb  = (u16*)alloc(1024ull * 1024 * 2);
  u16* wkb  = (u16*)alloc(1024ull * 1024 * 2);
  u16* wvb  = (u16*)alloc(1024ull * 1024 * 2);
  u16* wob  = (u16*)alloc(1024ull * 1024 * 2);
  u16* qbuf = (u16*)alloc(128ull * 1024 * 64 * 2);
  u16* kbuf = (u16*)alloc(128ull * 1024 * 64 * 2);
  u16* vbuf = (u16*)alloc(128ull * 1024 * 64 * 2);
  u16* vtb  = (u16*)alloc(128ull * 64 * 1024 * 2);
  u16* apre = (u16*)alloc(8192ull * 1024 * 2);
  float* mws = (float*)alloc(128ull * 1024 * 4);
  float* lws = (float*)alloc(128ull * 1024 * 4);

  float* out_attn = (float*)d_out;                  // [1024,8,1024]
  float* out_avg  = out_attn + 8388608;             // [8,1024,1024]
  float* out_w    = out_avg + 8388608;              // [8,16,1024,1024]

  k_cvt3<<<dim3(8192, 3), 256, 0, stream>>>(query, key_, value, xq, xk, xv);
  k_cvt4<<<dim3(1024, 4), 256, 0, stream>>>(Wq, Wk, Wv, Wo, wqb, wkb, wvb, wob);

  k_gemm_qkv<<<dim3(64, 8, 3), 256, 0, stream>>>(xq, xk, xv, wqb, wkb, wvb,
                                                 bq, bk, bv, qbuf, kbuf, vbuf);

  k_transpose<<<dim3(16, 128), 256, 0, stream>>>(vbuf, vtb);
  k_attn<<<dim3(128, 8), 256, 0, stream>>>(qbuf, kbuf, vtb, mws, lws, apre);
  k_weights<<<256, 512, 0, stream>>>(qbuf, kbuf, mws, lws, out_w, out_avg);
  k_gemm_o<<<dim3(64, 8), 256, 0, stream>>>(apre, wob, bo, out_attn);
}